// Round 11
// baseline (236.434 us; speedup 1.0000x reference)
//
#include <hip/hip_runtime.h>

#define D    2048
#define NB   32
#define BD   64
#define HD   128
#define WSZ  (NB * HD * BD)     // 262144 elems per weight matrix
#define TSZ  (16384 * 64)       // 1048576 elems per activation block-tile

typedef __attribute__((ext_vector_type(8))) short short8;
typedef __attribute__((ext_vector_type(4))) float floatx4;

static __device__ __forceinline__ unsigned short f2bf(float f) {
  union { float f; unsigned u; } v; v.f = f;
  return (unsigned short)((v.u + 0x7FFFu + ((v.u >> 16) & 1u)) >> 16);
}
static __device__ __forceinline__ float bf2f(unsigned short h) {
  union { unsigned u; float f; } v; v.u = ((unsigned)h) << 16;
  return v.f;
}
static __device__ __forceinline__ unsigned fbits(float f) {
  union { float f; unsigned u; } v; v.f = f; return v.u;
}
// TRUNCATION bf16x2 pack in ONE v_perm_b32 (validated r9/r10, absmax 384 < 586)
static __device__ __forceinline__ unsigned pkt(float a, float b) {
  return __builtin_amdgcn_perm(fbits(b), fbits(a), 0x07060302u);
}
static __device__ __forceinline__ float fast_exp2(float x) {
  float r; asm("v_exp_f32 %0, %1" : "=v"(r) : "v"(x)); return r;
}
static __device__ __forceinline__ float fast_rcp(float x) {
  float r; asm("v_rcp_f32 %0, %1" : "=v"(r) : "v"(x)); return r;
}
// sigmoid-form GELU (validated r1-r10)
static __device__ __forceinline__ float gelu_f(float x) {
  float x2 = x * x;
  float w  = __builtin_fmaf(x2, -0.102943695f, -2.3022083f);
  float e  = fast_exp2(x * w);
  return x * fast_rcp(1.0f + e);
}

// ---------------------------------------------------------------------------
// Round-11: BLOCK-TILE activation layout  Yt[n][16384][64] (bf16).
//  - every mlp WG reads/writes ONE contiguous 16-32KB region (r10 audit:
//    the 64-col strips at 4-8KB stride were capping effective BW at 1.7TB/s;
//    harness's contiguous fill hits 6.9TB/s)
//  - mlp WG = 256 thr (4 waves, 1 block x 128 rows) -> 4-5 WGs/CU staggered
//    (breaks the barrier convoy: load-burst of one WG overlaps compute of
//    others)
//  - permutes = LDS gather kernels over 8-row bands, in-place on Yt
//  - compute core unchanged from r10 (zero-DS H, k-permuted W2, pkt packs)
// ---------------------------------------------------------------------------
template<bool F32IN>
__global__ __launch_bounds__(256, 4) void mlp_layer(
    const float* __restrict__ xf,      // used when F32IN (row-major f32)
    unsigned short* yio,               // block-tile bf16: input (!F32IN) AND output
    const unsigned short* __restrict__ Wt1,  // [n][128][64] bf16, swizzled
    const unsigned short* __restrict__ Wt2,  // [n][64][128] bf16, slot-permuted+swizzled
    const float* __restrict__ b1,
    const float* __restrict__ b2) {
  __shared__ unsigned short Wlds[16384];     // 32KB: [0..8191]=W1t, [8192..]=W2t
  __shared__ float Blds[192];                // b1[0..127], b2[128..191]
  const int n     = blockIdx.x & 31;         // consecutive WGs = same rows, diff n
  const int chunk = blockIdx.x >> 5;         // 128 rows per chunk
  const int t = threadIdx.x, l = t & 63, wv = t >> 6;
  const int lr = l & 15, q = l >> 4;
  const int sw = (lr & 7) << 3;
  const int rbase = chunk * 128 + wv * 32 + lr;   // 2 tiles: +0, +16

  // ---- (1) issue weight-staging loads ----
  const unsigned short* s1 = Wt1 + n * 8192;
  const unsigned short* s2 = Wt2 + n * 8192;
  short8 sv1[4], sv2[4];
#pragma unroll
  for (int j = 0; j < 4; ++j) {
    sv1[j] = *(const short8*)&s1[(j * 256 + t) * 8];
    sv2[j] = *(const short8*)&s2[(j * 256 + t) * 8];
  }

  // ---- (2) issue bias loads ----
  float bv = 0.f;
  if (t < 128)      bv = b1[n * HD + t];
  else if (t < 192) bv = b2[n * BD + (t - 128)];

  // ---- (3) issue BOTH activation tile loads ----
  float4 uf[2][4];
  short8 xp[2][2];
  if constexpr (F32IN) {
#pragma unroll
    for (int p = 0; p < 2; ++p) {
      const float* xr = xf + (size_t)(rbase + p * 16) * D + n * BD + q * 8;
      uf[p][0] = *(const float4*)(xr);      uf[p][1] = *(const float4*)(xr + 4);
      uf[p][2] = *(const float4*)(xr + 32); uf[p][3] = *(const float4*)(xr + 36);
    }
  } else {
#pragma unroll
    for (int p = 0; p < 2; ++p) {
      const unsigned short* yr = yio + (size_t)n * TSZ + (size_t)(rbase + p * 16) * 64 + q * 8;
      xp[p][0] = *(const short8*)(yr); xp[p][1] = *(const short8*)(yr + 32);
    }
  }

  // ---- (4) compiler memory fence ----
  asm volatile("" ::: "memory");

  // ---- (5) LDS writes + barrier ----
#pragma unroll
  for (int j = 0; j < 4; ++j) {
    *(short8*)&Wlds[(j * 256 + t) * 8]        = sv1[j];
    *(short8*)&Wlds[8192 + (j * 256 + t) * 8] = sv2[j];
  }
  if (t < 192) Blds[t] = bv;

  __syncthreads();

  const unsigned short* w1p0 = &Wlds[lr * 64 + ((q * 8) ^ sw)];
  const unsigned short* w1p1 = &Wlds[lr * 64 + ((32 + q * 8) ^ sw)];
  const unsigned short* w2p0 = &Wlds[8192 + lr * 128 + ((q * 8) ^ sw)];
  const unsigned short* w2p1 = &Wlds[8192 + lr * 128 + ((32 + q * 8) ^ sw)];

#pragma unroll
  for (int i = 0; i < 2; ++i) {
    short8 xb0, xb1;
    if constexpr (F32IN) {
      union { unsigned u[4]; short8 s; } c0, c1;
      c0.u[0] = pkt(uf[i][0].x, uf[i][0].y);
      c0.u[1] = pkt(uf[i][0].z, uf[i][0].w);
      c0.u[2] = pkt(uf[i][1].x, uf[i][1].y);
      c0.u[3] = pkt(uf[i][1].z, uf[i][1].w);
      c1.u[0] = pkt(uf[i][2].x, uf[i][2].y);
      c1.u[1] = pkt(uf[i][2].z, uf[i][2].w);
      c1.u[2] = pkt(uf[i][3].x, uf[i][3].y);
      c1.u[3] = pkt(uf[i][3].z, uf[i][3].w);
      xb0 = c0.s; xb1 = c1.s;
    } else {
      xb0 = xp[i][0]; xb1 = xp[i][1];
    }

    floatx4 acc2[4];
#pragma unroll
    for (int ot = 0; ot < 4; ++ot) {
      const float4 bb = *(const float4*)&Blds[128 + ot * 16 + q * 4];
      floatx4 v; v[0] = bb.x; v[1] = bb.y; v[2] = bb.z; v[3] = bb.w;
      acc2[ot] = v;
    }
#pragma unroll
    for (int hf = 0; hf < 2; ++hf) {
      floatx4 acc1[4];
#pragma unroll
      for (int ot = 0; ot < 4; ++ot) {
        const float4 bb = *(const float4*)&Blds[hf * 64 + ot * 16 + q * 4];
        floatx4 v; v[0] = bb.x; v[1] = bb.y; v[2] = bb.z; v[3] = bb.w;
        acc1[ot] = v;
      }
#pragma unroll
      for (int ot = 0; ot < 4; ++ot) {
        const int off = (hf * 64 + ot * 16) * 64;
        short8 a0 = *(const short8*)&w1p0[off];
        short8 a1 = *(const short8*)&w1p1[off];
        acc1[ot] = __builtin_amdgcn_mfma_f32_16x16x32_bf16(a0, xb0, acc1[ot], 0, 0, 0);
        acc1[ot] = __builtin_amdgcn_mfma_f32_16x16x32_bf16(a1, xb1, acc1[ot], 0, 0, 0);
      }
      union { unsigned u[4]; short8 s; } hb0, hb1;
      hb0.u[0] = pkt(gelu_f(acc1[0][0]), gelu_f(acc1[0][1]));
      hb0.u[1] = pkt(gelu_f(acc1[0][2]), gelu_f(acc1[0][3]));
      hb0.u[2] = pkt(gelu_f(acc1[1][0]), gelu_f(acc1[1][1]));
      hb0.u[3] = pkt(gelu_f(acc1[1][2]), gelu_f(acc1[1][3]));
      hb1.u[0] = pkt(gelu_f(acc1[2][0]), gelu_f(acc1[2][1]));
      hb1.u[1] = pkt(gelu_f(acc1[2][2]), gelu_f(acc1[2][3]));
      hb1.u[2] = pkt(gelu_f(acc1[3][0]), gelu_f(acc1[3][1]));
      hb1.u[3] = pkt(gelu_f(acc1[3][2]), gelu_f(acc1[3][3]));
#pragma unroll
      for (int ot = 0; ot < 4; ++ot) {
        const int off = ot * 16 * 128 + hf * 64;
        short8 w0 = *(const short8*)&w2p0[off];
        short8 w1 = *(const short8*)&w2p1[off];
        acc2[ot] = __builtin_amdgcn_mfma_f32_16x16x32_bf16(w0, hb0.s, acc2[ot], 0, 0, 0);
        acc2[ot] = __builtin_amdgcn_mfma_f32_16x16x32_bf16(w1, hb1.s, acc2[ot], 0, 0, 0);
      }
    }

    // ---- store into block-tile (contiguous region per WG) ----
    unsigned short* yo = yio + (size_t)n * TSZ + (size_t)(rbase + i * 16) * 64;
#pragma unroll
    for (int ot = 0; ot < 4; ++ot) {
      if constexpr (F32IN) {
        uint2 ov;
        ov.x = pkt(acc2[ot][0], acc2[ot][1]);
        ov.y = pkt(acc2[ot][2], acc2[ot][3]);
        *(uint2*)&yo[ot * 16 + q * 4] = ov;
      } else {
        ushort4 ov;
        ov.x = f2bf(acc2[ot][0]);
        ov.y = f2bf(acc2[ot][1]);
        ov.z = f2bf(acc2[ot][2]);
        ov.w = f2bf(acc2[ot][3]);
        *(ushort4*)&yo[ot * 16 + q * 4] = ov;
      }
    }
  }
}

// ---------------------------------------------------------------------------
// Permute (layer-1 pre-mix), IN-PLACE on block-tile Yt.
// Zt[n'][2g+rr][b] = Yt[b%32][2g + b/32][rr*32 + n'].
// WG = 8-row band: stage 32 tiles x 8 rows x 128B (1KB contiguous chunks)
// into LDS (bank-swizzled), barrier, gather, write contiguous 128B rows.
// In-place safe: band is WG-exclusive, all reads from LDS after barrier.
// ---------------------------------------------------------------------------
__global__ __launch_bounds__(256) void permute_k(unsigned short* Y) {
  __shared__ unsigned short L[32 * 8 * 64];   // 32KB
  const int t = threadIdx.x;
  const int r0 = blockIdx.x * 8;
  {
    const int bb = t >> 3, lr = t & 7, sw8 = (bb & 7) << 3;
    const unsigned short* src = Y + (size_t)bb * TSZ + (size_t)(r0 + lr) * 64;
    unsigned short* Lrow = &L[bb * 512 + lr * 64];
    short8 v[8];
#pragma unroll
    for (int c8 = 0; c8 < 8; ++c8) v[c8] = *(const short8*)&src[c8 * 8];
#pragma unroll
    for (int c8 = 0; c8 < 8; ++c8) *(short8*)&Lrow[(c8 * 8) ^ sw8] = v[c8];
  }
  __syncthreads();
  const int np = t >> 3, lrp = t & 7;
  const int rr = lrp & 1, grow = lrp & ~1;
  const int colbase = rr * 32 + np;
  unsigned short* dst = Y + (size_t)np * TSZ + (size_t)(r0 + lrp) * 64;
#pragma unroll
  for (int c8 = 0; c8 < 8; ++c8) {
    short8 o;
#pragma unroll
    for (int k = 0; k < 8; ++k) {
      const int b  = c8 * 8 + k;
      const int tb = b & 31, gi = b >> 5;
      o[k] = (short)L[tb * 512 + (grow + gi) * 64 + (colbase ^ ((tb & 7) << 3))];
    }
    *(short8*)&dst[c8 * 8] = o;
  }
}

// ---------------------------------------------------------------------------
// Un-permute (layer-1 post-mix) + bf16->f32 store to ROW-MAJOR out.
// out(2g+rr, c) = Yt[(c%64)%32][2g + (c%64)/32][rr*32 + c/64].
// Same staging as permute_k; each wave writes 2 full rows (16KB contiguous).
// ---------------------------------------------------------------------------
__global__ __launch_bounds__(256) void unpermute_k(const unsigned short* __restrict__ Y,
                                                   float* __restrict__ out) {
  __shared__ unsigned short L[32 * 8 * 64];   // 32KB
  const int t = threadIdx.x;
  const int r0 = blockIdx.x * 8;
  {
    const int bb = t >> 3, lr = t & 7, sw8 = (bb & 7) << 3;
    const unsigned short* src = Y + (size_t)bb * TSZ + (size_t)(r0 + lr) * 64;
    unsigned short* Lrow = &L[bb * 512 + lr * 64];
    short8 v[8];
#pragma unroll
    for (int c8 = 0; c8 < 8; ++c8) v[c8] = *(const short8*)&src[c8 * 8];
#pragma unroll
    for (int c8 = 0; c8 < 8; ++c8) *(short8*)&Lrow[(c8 * 8) ^ sw8] = v[c8];
  }
  __syncthreads();
  const int lrp = t >> 5, cq = t & 31;
  const int rr = lrp & 1, grow = lrp & ~1;
  const int colbase = rr * 32 + cq;
  float* op = out + (size_t)(r0 + lrp) * D + cq * 64;
#pragma unroll
  for (int e4 = 0; e4 < 16; ++e4) {
    float4 f;
#pragma unroll
    for (int k = 0; k < 4; ++k) {
      const int e  = e4 * 4 + k;
      const int tb = e & 31, gi = e >> 5;
      const float v = bf2f(L[tb * 512 + (grow + gi) * 64 + (colbase ^ ((tb & 7) << 3))]);
      if      (k == 0) f.x = v;
      else if (k == 1) f.y = v;
      else if (k == 2) f.z = v;
      else             f.w = v;
    }
    *(float4*)&op[e4 * 4] = f;
  }
}

// W [n][R][C] f32 -> Wt [n][C][R] bf16, transposed + XOR-swizzled.
// W2 (odd segs) additionally k-slot-permuted (zero-DS H; validated r7-r10).
__global__ void prep_w_all(const float* __restrict__ W1_0, const float* __restrict__ W2_0,
                           const float* __restrict__ W1_1, const float* __restrict__ W2_1,
                           unsigned short* __restrict__ dst) {
  const int seg = blockIdx.x >> 10;
  const int id  = ((blockIdx.x & 1023) << 8) | threadIdx.x;
  const float* W; int R;
  if      (seg == 0) { W = W1_0; R = BD; }
  else if (seg == 1) { W = W2_0; R = HD; }
  else if (seg == 2) { W = W1_1; R = BD; }
  else               { W = W2_1; R = HD; }
  const int C   = (R == BD) ? HD : BD;
  const int n   = id >> 13;
  const int rem = id & 8191;
  const int c   = rem / R;
  const int r   = rem - c * R;
  const unsigned short val = f2bf(W[(n * R + r) * C + c]);
  if (seg & 1) {
    const int hf  = r >> 6, st = (r >> 5) & 1, blk = (r >> 4) & 1;
    const int qq  = (r & 15) >> 2, e = r & 3;
    const int slot = hf * 64 + st * 32 + qq * 8 + blk * 4 + e;
    dst[seg * WSZ + n * 8192 + c * HD + (slot ^ ((c & 7) << 3))] = val;
  } else {
    dst[seg * WSZ + n * 8192 + c * BD + (r ^ ((c & 7) << 3))] = val;
  }
}

extern "C" void kernel_launch(void* const* d_in, const int* in_sizes, int n_in,
                              void* d_out, int out_size, void* d_ws, size_t ws_size,
                              hipStream_t stream) {
  const float* x    = (const float*)d_in[0];
  const float* W1_0 = (const float*)d_in[1];
  const float* b1_0 = (const float*)d_in[2];
  const float* W2_0 = (const float*)d_in[3];
  const float* b2_0 = (const float*)d_in[4];
  const float* W1_1 = (const float*)d_in[5];
  const float* b1_1 = (const float*)d_in[6];
  const float* W2_1 = (const float*)d_in[7];
  const float* b2_1 = (const float*)d_in[8];
  float* out = (float*)d_out;

  // ws layout: [Wt: 4 x 512KB = 2MB][Yt block-tile: 64MB]
  unsigned short* Wt = (unsigned short*)d_ws;
  unsigned short* Yt = Wt + 4 * WSZ;

  prep_w_all<<<4096, 256, 0, stream>>>(W1_0, W2_0, W1_1, W2_1, Wt);
  mlp_layer<true ><<<4096, 256, 0, stream>>>(x, Yt, Wt, Wt + WSZ, b1_0, b2_0);
  permute_k<<<2048, 256, 0, stream>>>(Yt);
  mlp_layer<false><<<4096, 256, 0, stream>>>(nullptr, Yt, Wt + 2 * WSZ, Wt + 3 * WSZ, b1_1, b2_1);
  unpermute_k<<<2048, 256, 0, stream>>>(Yt, out);
}

// Round 12
// 171.910 us; speedup vs baseline: 1.3753x; 1.3753x over previous
//
#include <hip/hip_runtime.h>

#define D    2048
#define NB   32
#define BD   64
#define HD   128
#define WSZ  (NB * HD * BD)     // 262144 elems per weight matrix
#define TSZ  (16384 * 64)       // 1048576 elems per activation block-tile

typedef __attribute__((ext_vector_type(8))) short short8;
typedef __attribute__((ext_vector_type(4))) float floatx4;

static __device__ __forceinline__ unsigned short f2bf(float f) {
  union { float f; unsigned u; } v; v.f = f;
  return (unsigned short)((v.u + 0x7FFFu + ((v.u >> 16) & 1u)) >> 16);
}
static __device__ __forceinline__ float bf2f(unsigned short h) {
  union { unsigned u; float f; } v; v.u = ((unsigned)h) << 16;
  return v.f;
}
static __device__ __forceinline__ unsigned fbits(float f) {
  union { float f; unsigned u; } v; v.f = f; return v.u;
}
// TRUNCATION bf16x2 pack in ONE v_perm_b32 (validated r9-r11, absmax 384 < 586)
static __device__ __forceinline__ unsigned pkt(float a, float b) {
  return __builtin_amdgcn_perm(fbits(b), fbits(a), 0x07060302u);
}
static __device__ __forceinline__ float fast_exp2(float x) {
  float r; asm("v_exp_f32 %0, %1" : "=v"(r) : "v"(x)); return r;
}
static __device__ __forceinline__ float fast_rcp(float x) {
  float r; asm("v_rcp_f32 %0, %1" : "=v"(r) : "v"(x)); return r;
}
// sigmoid-form GELU (validated r1-r11)
static __device__ __forceinline__ float gelu_f(float x) {
  float x2 = x * x;
  float w  = __builtin_fmaf(x2, -0.102943695f, -2.3022083f);
  float e  = fast_exp2(x * w);
  return x * fast_rcp(1.0f + e);
}

// ---------------------------------------------------------------------------
// mlp_layer: unchanged from r11 (block-tile Yt[n][16384][64]; contiguous WG
// regions; zero-DS H via k-permuted W2; pkt packs; LDS weights; load fence).
// ---------------------------------------------------------------------------
template<bool F32IN>
__global__ __launch_bounds__(256, 4) void mlp_layer(
    const float* __restrict__ xf,
    unsigned short* yio,
    const unsigned short* __restrict__ Wt1,
    const unsigned short* __restrict__ Wt2,
    const float* __restrict__ b1,
    const float* __restrict__ b2) {
  __shared__ unsigned short Wlds[16384];
  __shared__ float Blds[192];
  const int n     = blockIdx.x & 31;
  const int chunk = blockIdx.x >> 5;
  const int t = threadIdx.x, l = t & 63, wv = t >> 6;
  const int lr = l & 15, q = l >> 4;
  const int sw = (lr & 7) << 3;
  const int rbase = chunk * 128 + wv * 32 + lr;

  const unsigned short* s1 = Wt1 + n * 8192;
  const unsigned short* s2 = Wt2 + n * 8192;
  short8 sv1[4], sv2[4];
#pragma unroll
  for (int j = 0; j < 4; ++j) {
    sv1[j] = *(const short8*)&s1[(j * 256 + t) * 8];
    sv2[j] = *(const short8*)&s2[(j * 256 + t) * 8];
  }
  float bv = 0.f;
  if (t < 128)      bv = b1[n * HD + t];
  else if (t < 192) bv = b2[n * BD + (t - 128)];

  float4 uf[2][4];
  short8 xp[2][2];
  if constexpr (F32IN) {
#pragma unroll
    for (int p = 0; p < 2; ++p) {
      const float* xr = xf + (size_t)(rbase + p * 16) * D + n * BD + q * 8;
      uf[p][0] = *(const float4*)(xr);      uf[p][1] = *(const float4*)(xr + 4);
      uf[p][2] = *(const float4*)(xr + 32); uf[p][3] = *(const float4*)(xr + 36);
    }
  } else {
#pragma unroll
    for (int p = 0; p < 2; ++p) {
      const unsigned short* yr = yio + (size_t)n * TSZ + (size_t)(rbase + p * 16) * 64 + q * 8;
      xp[p][0] = *(const short8*)(yr); xp[p][1] = *(const short8*)(yr + 32);
    }
  }

  asm volatile("" ::: "memory");

#pragma unroll
  for (int j = 0; j < 4; ++j) {
    *(short8*)&Wlds[(j * 256 + t) * 8]        = sv1[j];
    *(short8*)&Wlds[8192 + (j * 256 + t) * 8] = sv2[j];
  }
  if (t < 192) Blds[t] = bv;

  __syncthreads();

  const unsigned short* w1p0 = &Wlds[lr * 64 + ((q * 8) ^ sw)];
  const unsigned short* w1p1 = &Wlds[lr * 64 + ((32 + q * 8) ^ sw)];
  const unsigned short* w2p0 = &Wlds[8192 + lr * 128 + ((q * 8) ^ sw)];
  const unsigned short* w2p1 = &Wlds[8192 + lr * 128 + ((32 + q * 8) ^ sw)];

#pragma unroll
  for (int i = 0; i < 2; ++i) {
    short8 xb0, xb1;
    if constexpr (F32IN) {
      union { unsigned u[4]; short8 s; } c0, c1;
      c0.u[0] = pkt(uf[i][0].x, uf[i][0].y);
      c0.u[1] = pkt(uf[i][0].z, uf[i][0].w);
      c0.u[2] = pkt(uf[i][1].x, uf[i][1].y);
      c0.u[3] = pkt(uf[i][1].z, uf[i][1].w);
      c1.u[0] = pkt(uf[i][2].x, uf[i][2].y);
      c1.u[1] = pkt(uf[i][2].z, uf[i][2].w);
      c1.u[2] = pkt(uf[i][3].x, uf[i][3].y);
      c1.u[3] = pkt(uf[i][3].z, uf[i][3].w);
      xb0 = c0.s; xb1 = c1.s;
    } else {
      xb0 = xp[i][0]; xb1 = xp[i][1];
    }

    floatx4 acc2[4];
#pragma unroll
    for (int ot = 0; ot < 4; ++ot) {
      const float4 bb = *(const float4*)&Blds[128 + ot * 16 + q * 4];
      floatx4 v; v[0] = bb.x; v[1] = bb.y; v[2] = bb.z; v[3] = bb.w;
      acc2[ot] = v;
    }
#pragma unroll
    for (int hf = 0; hf < 2; ++hf) {
      floatx4 acc1[4];
#pragma unroll
      for (int ot = 0; ot < 4; ++ot) {
        const float4 bb = *(const float4*)&Blds[hf * 64 + ot * 16 + q * 4];
        floatx4 v; v[0] = bb.x; v[1] = bb.y; v[2] = bb.z; v[3] = bb.w;
        acc1[ot] = v;
      }
#pragma unroll
      for (int ot = 0; ot < 4; ++ot) {
        const int off = (hf * 64 + ot * 16) * 64;
        short8 a0 = *(const short8*)&w1p0[off];
        short8 a1 = *(const short8*)&w1p1[off];
        acc1[ot] = __builtin_amdgcn_mfma_f32_16x16x32_bf16(a0, xb0, acc1[ot], 0, 0, 0);
        acc1[ot] = __builtin_amdgcn_mfma_f32_16x16x32_bf16(a1, xb1, acc1[ot], 0, 0, 0);
      }
      union { unsigned u[4]; short8 s; } hb0, hb1;
      hb0.u[0] = pkt(gelu_f(acc1[0][0]), gelu_f(acc1[0][1]));
      hb0.u[1] = pkt(gelu_f(acc1[0][2]), gelu_f(acc1[0][3]));
      hb0.u[2] = pkt(gelu_f(acc1[1][0]), gelu_f(acc1[1][1]));
      hb0.u[3] = pkt(gelu_f(acc1[1][2]), gelu_f(acc1[1][3]));
      hb1.u[0] = pkt(gelu_f(acc1[2][0]), gelu_f(acc1[2][1]));
      hb1.u[1] = pkt(gelu_f(acc1[2][2]), gelu_f(acc1[2][3]));
      hb1.u[2] = pkt(gelu_f(acc1[3][0]), gelu_f(acc1[3][1]));
      hb1.u[3] = pkt(gelu_f(acc1[3][2]), gelu_f(acc1[3][3]));
#pragma unroll
      for (int ot = 0; ot < 4; ++ot) {
        const int off = ot * 16 * 128 + hf * 64;
        short8 w0 = *(const short8*)&w2p0[off];
        short8 w1 = *(const short8*)&w2p1[off];
        acc2[ot] = __builtin_amdgcn_mfma_f32_16x16x32_bf16(w0, hb0.s, acc2[ot], 0, 0, 0);
        acc2[ot] = __builtin_amdgcn_mfma_f32_16x16x32_bf16(w1, hb1.s, acc2[ot], 0, 0, 0);
      }
    }

    unsigned short* yo = yio + (size_t)n * TSZ + (size_t)(rbase + i * 16) * 64;
#pragma unroll
    for (int ot = 0; ot < 4; ++ot) {
      if constexpr (F32IN) {
        uint2 ov;
        ov.x = pkt(acc2[ot][0], acc2[ot][1]);
        ov.y = pkt(acc2[ot][2], acc2[ot][3]);
        *(uint2*)&yo[ot * 16 + q * 4] = ov;
      } else {
        ushort4 ov;
        ov.x = f2bf(acc2[ot][0]);
        ov.y = f2bf(acc2[ot][1]);
        ov.z = f2bf(acc2[ot][2]);
        ov.w = f2bf(acc2[ot][3]);
        *(ushort4*)&yo[ot * 16 + q * 4] = ov;
      }
    }
  }
}

// ---------------------------------------------------------------------------
// permute_k (r12): in-place on Yt; EVERY global access is a 1KB-contiguous
// wave instruction. Band = 8 rows; wave w handles tiles w*8..w*8+7 on both
// sides. LDS staged with (n+row)&7 granule-XOR; gather is 8 scalar reads
// per short8 (~8-way conflict, off critical path).
// Mapping (validated r11): Z[np][r][fp] = Y[fp&31][(r&~1)|(fp>>5)][(r&1)*32+np]
// ---------------------------------------------------------------------------
__global__ __launch_bounds__(256) void permute_k(unsigned short* Y) {
  __shared__ unsigned short L[32 * 512];   // 32KB
  const int t = threadIdx.x, w = t >> 6, j = t & 63;
  const size_t r0 = (size_t)blockIdx.x * 8;
#pragma unroll
  for (int c = 0; c < 8; ++c) {
    const int n = w * 8 + c;
    short8 v = *(const short8*)(Y + (size_t)n * TSZ + r0 * 64 + j * 8);
    const int row = j >> 3;
    const int gp = (j & 7) ^ ((n + row) & 7);
    *(short8*)&L[n * 512 + row * 64 + gp * 8] = v;
  }
  __syncthreads();
#pragma unroll
  for (int c = 0; c < 8; ++c) {
    const int np  = w * 8 + c;
    const int row = j >> 3;
    short8 o;
#pragma unroll
    for (int k = 0; k < 8; ++k) {
      const int fp   = (j & 7) * 8 + k;
      const int n    = fp & 31;
      const int srow = (row & ~1) | (fp >> 5);
      const int scol = (row & 1) * 32 + np;
      const int g    = ((scol >> 3) ^ ((n + srow) & 7));
      o[k] = (short)L[n * 512 + srow * 64 + g * 8 + (scol & 7)];
    }
    *(short8*)(Y + (size_t)np * TSZ + r0 * 64 + j * 8) = o;
  }
}

// ---------------------------------------------------------------------------
// unpermute_k (r12): bf16 block-tile -> f32 row-major out. Writes are
// 1KB-contiguous per wave instruction (lane j -> float4 at col i*256+j*4);
// each wave assembles 2 full output rows. 4 scalar LDS reads per float4.
// Mapping (validated r11): out(r,c) = Y[(c&63)&31][(r&~1)|((c&63)>>5)][(r&1)*32 + (c>>6)]
// ---------------------------------------------------------------------------
__global__ __launch_bounds__(256) void unpermute_k(const unsigned short* __restrict__ Y,
                                                   float* __restrict__ out) {
  __shared__ unsigned short L[32 * 512];   // 32KB
  const int t = threadIdx.x, w = t >> 6, j = t & 63;
  const size_t r0 = (size_t)blockIdx.x * 8;
#pragma unroll
  for (int c = 0; c < 8; ++c) {
    const int n = w * 8 + c;
    short8 v = *(const short8*)(Y + (size_t)n * TSZ + r0 * 64 + j * 8);
    const int row = j >> 3;
    const int gp = (j & 7) ^ ((n + row) & 7);
    *(short8*)&L[n * 512 + row * 64 + gp * 8] = v;
  }
  __syncthreads();
#pragma unroll
  for (int p = 0; p < 2; ++p) {
    const int rloc = w * 2 + p;
    float* op = out + (r0 + rloc) * (size_t)D;
#pragma unroll
    for (int i = 0; i < 8; ++i) {
      const int cbase = i * 256 + j * 4;
      float4 f;
#pragma unroll
      for (int e = 0; e < 4; ++e) {
        const int cc   = cbase + e;
        const int np   = cc >> 6, fp = cc & 63;
        const int n    = fp & 31;
        const int srow = (rloc & ~1) | (fp >> 5);
        const int scol = (rloc & 1) * 32 + np;
        const int g    = ((scol >> 3) ^ ((n + srow) & 7));
        const float v  = bf2f(L[n * 512 + srow * 64 + g * 8 + (scol & 7)]);
        if      (e == 0) f.x = v;
        else if (e == 1) f.y = v;
        else if (e == 2) f.z = v;
        else             f.w = v;
      }
      *(float4*)&op[cbase] = f;
    }
  }
}

// W [n][R][C] f32 -> Wt [n][C][R] bf16, transposed + XOR-swizzled.
// W2 (odd segs) additionally k-slot-permuted (zero-DS H; validated r7-r11).
__global__ void prep_w_all(const float* __restrict__ W1_0, const float* __restrict__ W2_0,
                           const float* __restrict__ W1_1, const float* __restrict__ W2_1,
                           unsigned short* __restrict__ dst) {
  const int seg = blockIdx.x >> 10;
  const int id  = ((blockIdx.x & 1023) << 8) | threadIdx.x;
  const float* W; int R;
  if      (seg == 0) { W = W1_0; R = BD; }
  else if (seg == 1) { W = W2_0; R = HD; }
  else if (seg == 2) { W = W1_1; R = BD; }
  else               { W = W2_1; R = HD; }
  const int C   = (R == BD) ? HD : BD;
  const int n   = id >> 13;
  const int rem = id & 8191;
  const int c   = rem / R;
  const int r   = rem - c * R;
  const unsigned short val = f2bf(W[(n * R + r) * C + c]);
  if (seg & 1) {
    const int hf  = r >> 6, st = (r >> 5) & 1, blk = (r >> 4) & 1;
    const int qq  = (r & 15) >> 2, e = r & 3;
    const int slot = hf * 64 + st * 32 + qq * 8 + blk * 4 + e;
    dst[seg * WSZ + n * 8192 + c * HD + (slot ^ ((c & 7) << 3))] = val;
  } else {
    dst[seg * WSZ + n * 8192 + c * BD + (r ^ ((c & 7) << 3))] = val;
  }
}

extern "C" void kernel_launch(void* const* d_in, const int* in_sizes, int n_in,
                              void* d_out, int out_size, void* d_ws, size_t ws_size,
                              hipStream_t stream) {
  const float* x    = (const float*)d_in[0];
  const float* W1_0 = (const float*)d_in[1];
  const float* b1_0 = (const float*)d_in[2];
  const float* W2_0 = (const float*)d_in[3];
  const float* b2_0 = (const float*)d_in[4];
  const float* W1_1 = (const float*)d_in[5];
  const float* b1_1 = (const float*)d_in[6];
  const float* W2_1 = (const float*)d_in[7];
  const float* b2_1 = (const float*)d_in[8];
  float* out = (float*)d_out;

  // ws layout: [Wt: 4 x 512KB = 2MB][Yt block-tile: 64MB]
  unsigned short* Wt = (unsigned short*)d_ws;
  unsigned short* Yt = Wt + 4 * WSZ;

  prep_w_all<<<4096, 256, 0, stream>>>(W1_0, W2_0, W1_1, W2_1, Wt);
  mlp_layer<true ><<<4096, 256, 0, stream>>>(x, Yt, Wt, Wt + WSZ, b1_0, b2_0);
  permute_k<<<2048, 256, 0, stream>>>(Yt);
  mlp_layer<false><<<4096, 256, 0, stream>>>(nullptr, Yt, Wt + 2 * WSZ, Wt + 3 * WSZ, b1_1, b2_1);
  unpermute_k<<<2048, 256, 0, stream>>>(Yt, out);
}

// Round 13
// 140.583 us; speedup vs baseline: 1.6818x; 1.2228x over previous
//
#include <hip/hip_runtime.h>

#define D    2048
#define NB   32
#define BD   64
#define HD   128
#define WSZ  (NB * HD * BD)     // 262144 elems per weight matrix
#define TSZ  (16384 * 64)       // 1048576 elems per activation block-tile

typedef __attribute__((ext_vector_type(8))) short short8;
typedef __attribute__((ext_vector_type(4))) float floatx4;

static __device__ __forceinline__ unsigned short f2bf(float f) {
  union { float f; unsigned u; } v; v.f = f;
  return (unsigned short)((v.u + 0x7FFFu + ((v.u >> 16) & 1u)) >> 16);
}
static __device__ __forceinline__ float bf2f(unsigned short h) {
  union { unsigned u; float f; } v; v.u = ((unsigned)h) << 16;
  return v.f;
}
static __device__ __forceinline__ unsigned fbits(float f) {
  union { float f; unsigned u; } v; v.f = f; return v.u;
}
// truncation bf16 (scalar) and bf16x2 pack (validated r9-r12, absmax 384 < 586)
static __device__ __forceinline__ unsigned short tbf(float f) {
  return (unsigned short)(fbits(f) >> 16);
}
static __device__ __forceinline__ unsigned pkt(float a, float b) {
  return __builtin_amdgcn_perm(fbits(b), fbits(a), 0x07060302u);
}
static __device__ __forceinline__ float fast_exp2(float x) {
  float r; asm("v_exp_f32 %0, %1" : "=v"(r) : "v"(x)); return r;
}
static __device__ __forceinline__ float fast_rcp(float x) {
  float r; asm("v_rcp_f32 %0, %1" : "=v"(r) : "v"(x)); return r;
}
// sigmoid-form GELU (validated r1-r12)
static __device__ __forceinline__ float gelu_f(float x) {
  float x2 = x * x;
  float w  = __builtin_fmaf(x2, -0.102943695f, -2.3022083f);
  float e  = fast_exp2(x * w);
  return x * fast_rcp(1.0f + e);
}

// ---------------------------------------------------------------------------
// mlp0: layer 0, reads x (row-major f32), writes Yt0[n][fo][r] TRANSPOSED
// per tile via in-WG LDS transpose. Compute core = r12 (zero-DS H via
// k-permuted W2, pkt packs, LDS weights, load fence).
// ---------------------------------------------------------------------------
__global__ __launch_bounds__(256, 3) void mlp0_k(
    const float* __restrict__ xf,
    unsigned short* __restrict__ Yt0,        // [n][64][16384]
    const unsigned short* __restrict__ Wt1,
    const unsigned short* __restrict__ Wt2,
    const float* __restrict__ b1, const float* __restrict__ b2) {
  __shared__ unsigned short Wlds[16384];     // 32 KB
  __shared__ unsigned short Olds[64 * 128];  // 16 KB: [fo][rl ^ ((fo&7)<<3)]
  __shared__ float Blds[192];
  const int n     = blockIdx.x & 31;
  const int chunk = blockIdx.x >> 5;
  const int t = threadIdx.x, l = t & 63, wv = t >> 6;
  const int lr = l & 15, q = l >> 4;
  const int sw = (lr & 7) << 3;
  const int rbase = chunk * 128 + wv * 32 + lr;

  // (1) weight-staging loads
  const unsigned short* s1 = Wt1 + n * 8192;
  const unsigned short* s2 = Wt2 + n * 8192;
  short8 sv1[4], sv2[4];
#pragma unroll
  for (int j = 0; j < 4; ++j) {
    sv1[j] = *(const short8*)&s1[(j * 256 + t) * 8];
    sv2[j] = *(const short8*)&s2[(j * 256 + t) * 8];
  }
  // (2) bias loads
  float bv = 0.f;
  if (t < 128)      bv = b1[n * HD + t];
  else if (t < 192) bv = b2[n * BD + (t - 128)];
  // (3) both activation tile loads
  float4 uf[2][4];
#pragma unroll
  for (int p = 0; p < 2; ++p) {
    const float* xr = xf + (size_t)(rbase + p * 16) * D + n * BD + q * 8;
    uf[p][0] = *(const float4*)(xr);      uf[p][1] = *(const float4*)(xr + 4);
    uf[p][2] = *(const float4*)(xr + 32); uf[p][3] = *(const float4*)(xr + 36);
  }
  // (4) fence: loads may not sink below
  asm volatile("" ::: "memory");
  // (5) LDS writes + barrier
#pragma unroll
  for (int j = 0; j < 4; ++j) {
    *(short8*)&Wlds[(j * 256 + t) * 8]        = sv1[j];
    *(short8*)&Wlds[8192 + (j * 256 + t) * 8] = sv2[j];
  }
  if (t < 192) Blds[t] = bv;
  __syncthreads();

  const unsigned short* w1p0 = &Wlds[lr * 64 + ((q * 8) ^ sw)];
  const unsigned short* w1p1 = &Wlds[lr * 64 + ((32 + q * 8) ^ sw)];
  const unsigned short* w2p0 = &Wlds[8192 + lr * 128 + ((q * 8) ^ sw)];
  const unsigned short* w2p1 = &Wlds[8192 + lr * 128 + ((32 + q * 8) ^ sw)];

#pragma unroll
  for (int i = 0; i < 2; ++i) {
    short8 xb0, xb1;
    {
      union { unsigned u[4]; short8 s; } c0, c1;
      c0.u[0] = pkt(uf[i][0].x, uf[i][0].y);
      c0.u[1] = pkt(uf[i][0].z, uf[i][0].w);
      c0.u[2] = pkt(uf[i][1].x, uf[i][1].y);
      c0.u[3] = pkt(uf[i][1].z, uf[i][1].w);
      c1.u[0] = pkt(uf[i][2].x, uf[i][2].y);
      c1.u[1] = pkt(uf[i][2].z, uf[i][2].w);
      c1.u[2] = pkt(uf[i][3].x, uf[i][3].y);
      c1.u[3] = pkt(uf[i][3].z, uf[i][3].w);
      xb0 = c0.s; xb1 = c1.s;
    }
    floatx4 acc2[4];
#pragma unroll
    for (int ot = 0; ot < 4; ++ot) {
      const float4 bb = *(const float4*)&Blds[128 + ot * 16 + q * 4];
      floatx4 v; v[0] = bb.x; v[1] = bb.y; v[2] = bb.z; v[3] = bb.w;
      acc2[ot] = v;
    }
#pragma unroll
    for (int hf = 0; hf < 2; ++hf) {
      floatx4 acc1[4];
#pragma unroll
      for (int ot = 0; ot < 4; ++ot) {
        const float4 bb = *(const float4*)&Blds[hf * 64 + ot * 16 + q * 4];
        floatx4 v; v[0] = bb.x; v[1] = bb.y; v[2] = bb.z; v[3] = bb.w;
        acc1[ot] = v;
      }
#pragma unroll
      for (int ot = 0; ot < 4; ++ot) {
        const int off = (hf * 64 + ot * 16) * 64;
        short8 a0 = *(const short8*)&w1p0[off];
        short8 a1 = *(const short8*)&w1p1[off];
        acc1[ot] = __builtin_amdgcn_mfma_f32_16x16x32_bf16(a0, xb0, acc1[ot], 0, 0, 0);
        acc1[ot] = __builtin_amdgcn_mfma_f32_16x16x32_bf16(a1, xb1, acc1[ot], 0, 0, 0);
      }
      union { unsigned u[4]; short8 s; } hb0, hb1;
      hb0.u[0] = pkt(gelu_f(acc1[0][0]), gelu_f(acc1[0][1]));
      hb0.u[1] = pkt(gelu_f(acc1[0][2]), gelu_f(acc1[0][3]));
      hb0.u[2] = pkt(gelu_f(acc1[1][0]), gelu_f(acc1[1][1]));
      hb0.u[3] = pkt(gelu_f(acc1[1][2]), gelu_f(acc1[1][3]));
      hb1.u[0] = pkt(gelu_f(acc1[2][0]), gelu_f(acc1[2][1]));
      hb1.u[1] = pkt(gelu_f(acc1[2][2]), gelu_f(acc1[2][3]));
      hb1.u[2] = pkt(gelu_f(acc1[3][0]), gelu_f(acc1[3][1]));
      hb1.u[3] = pkt(gelu_f(acc1[3][2]), gelu_f(acc1[3][3]));
#pragma unroll
      for (int ot = 0; ot < 4; ++ot) {
        const int off = ot * 16 * 128 + hf * 64;
        short8 w0 = *(const short8*)&w2p0[off];
        short8 w1 = *(const short8*)&w2p1[off];
        acc2[ot] = __builtin_amdgcn_mfma_f32_16x16x32_bf16(w0, hb0.s, acc2[ot], 0, 0, 0);
        acc2[ot] = __builtin_amdgcn_mfma_f32_16x16x32_bf16(w1, hb1.s, acc2[ot], 0, 0, 0);
      }
    }
    // scatter acc2 into Olds (transposed buffer), truncation bf16
    const int rl = wv * 32 + i * 16 + lr;
#pragma unroll
    for (int ot = 0; ot < 4; ++ot) {
#pragma unroll
      for (int e = 0; e < 4; ++e) {
        const int fo = ot * 16 + q * 4 + e;
        Olds[fo * 128 + (rl ^ ((fo & 7) << 3))] = tbf(acc2[ot][e]);
      }
    }
  }
  __syncthreads();   // Olds complete across all waves

  // transposed write-out: per inst, 2 fo-chunks of 256B contiguous
  const int j = t & 63, w = t >> 6;
#pragma unroll
  for (int ii = 0; ii < 8; ++ii) {
    const int fo = w * 16 + ii * 2 + (j >> 5);
    const int r4 = (j & 31) * 4;
    const int G  = (fo & 7) << 3;
    uint2 v = *(const uint2*)&Olds[fo * 128 + (r4 ^ G)];
    *(uint2*)(Yt0 + (size_t)n * TSZ + (size_t)fo * 16384 + chunk * 128 + r4) = v;
  }
}

// ---------------------------------------------------------------------------
// mlp1: layer 1. Reads its PERMUTED operand straight from Yt0 (permute
// folded in): block np needs cols {np,32+np} of every tile = 64 contiguous
// 256B chunks, staged to Xl[p][row][n'] (n'-XOR swizzled so B-frags are
// single ds_read_b128). Writes Yt1[np][r][a] (block-tile, RNE bf16).
// Mapping (validated r11/r12): Z[np][R][fp] = Y[fp&31][(R&~1)+(fp>>5)][(R&1)*32+np]
// ---------------------------------------------------------------------------
__global__ __launch_bounds__(256, 3) void mlp1_k(
    const unsigned short* __restrict__ Yt0,   // [n][64][16384]
    unsigned short* __restrict__ Yt1,         // [np][16384][64]
    const unsigned short* __restrict__ Wt1,
    const unsigned short* __restrict__ Wt2,
    const float* __restrict__ b1, const float* __restrict__ b2) {
  __shared__ unsigned short Wlds[16384];       // 32 KB
  __shared__ unsigned short Xl[2 * 128 * 32];  // 16 KB: [p][row][n' ^ (((row>>1)&3)<<3)]
  __shared__ float Blds[192];
  const int np    = blockIdx.x & 31;
  const int chunk = blockIdx.x >> 5;
  const int t = threadIdx.x, l = t & 63, wv = t >> 6;
  const int lr = l & 15, q = l >> 4;
  const int sw = (lr & 7) << 3;

  // (1) weight-staging loads
  const unsigned short* s1 = Wt1 + np * 8192;
  const unsigned short* s2 = Wt2 + np * 8192;
  short8 sv1[4], sv2[4];
#pragma unroll
  for (int j = 0; j < 4; ++j) {
    sv1[j] = *(const short8*)&s1[(j * 256 + t) * 8];
    sv2[j] = *(const short8*)&s2[(j * 256 + t) * 8];
  }
  // (2) bias loads
  float bv = 0.f;
  if (t < 128)      bv = b1[np * HD + t];
  else if (t < 192) bv = b2[np * BD + (t - 128)];
  // (3) permuted-operand stage loads: chunk c=(p,n'), 4 threads/chunk, 64B each
  const int c = t >> 2, sub = t & 3;
  const int sp = c >> 5, sn = c & 31;
  const unsigned short* src = Yt0 + (size_t)sn * TSZ + (size_t)(sp * 32 + np) * 16384
                              + chunk * 128 + sub * 32;
  short8 sx[4];
#pragma unroll
  for (int m = 0; m < 4; ++m) sx[m] = *(const short8*)(src + m * 8);

  // (4) fence
  asm volatile("" ::: "memory");
  // (5) LDS writes + barrier
#pragma unroll
  for (int j = 0; j < 4; ++j) {
    *(short8*)&Wlds[(j * 256 + t) * 8]        = sv1[j];
    *(short8*)&Wlds[8192 + (j * 256 + t) * 8] = sv2[j];
  }
  if (t < 192) Blds[t] = bv;
#pragma unroll
  for (int m = 0; m < 4; ++m) {
#pragma unroll
    for (int k = 0; k < 8; ++k) {
      const int row = sub * 32 + m * 8 + k;
      Xl[sp * 4096 + row * 32 + (sn ^ (((row >> 1) & 3) << 3))] = (unsigned short)sx[m][k];
    }
  }
  __syncthreads();

  const unsigned short* w1p0 = &Wlds[lr * 64 + ((q * 8) ^ sw)];
  const unsigned short* w1p1 = &Wlds[lr * 64 + ((32 + q * 8) ^ sw)];
  const unsigned short* w2p0 = &Wlds[8192 + lr * 128 + ((q * 8) ^ sw)];
  const unsigned short* w2p1 = &Wlds[8192 + lr * 128 + ((32 + q * 8) ^ sw)];
  const int p = lr & 1;

#pragma unroll
  for (int i = 0; i < 2; ++i) {
    const int rloc = (wv * 32 + i * 16 + lr) & ~1;
    const int g0   = ((rloc >> 1) & 3) << 3;
    short8 xb0 = *(const short8*)&Xl[p * 4096 + rloc * 32 + ((q * 8) ^ g0)];
    short8 xb1 = *(const short8*)&Xl[p * 4096 + (rloc + 1) * 32 + ((q * 8) ^ g0)];

    floatx4 acc2[4];
#pragma unroll
    for (int ot = 0; ot < 4; ++ot) {
      const float4 bb = *(const float4*)&Blds[128 + ot * 16 + q * 4];
      floatx4 v; v[0] = bb.x; v[1] = bb.y; v[2] = bb.z; v[3] = bb.w;
      acc2[ot] = v;
    }
#pragma unroll
    for (int hf = 0; hf < 2; ++hf) {
      floatx4 acc1[4];
#pragma unroll
      for (int ot = 0; ot < 4; ++ot) {
        const float4 bb = *(const float4*)&Blds[hf * 64 + ot * 16 + q * 4];
        floatx4 v; v[0] = bb.x; v[1] = bb.y; v[2] = bb.z; v[3] = bb.w;
        acc1[ot] = v;
      }
#pragma unroll
      for (int ot = 0; ot < 4; ++ot) {
        const int off = (hf * 64 + ot * 16) * 64;
        short8 a0 = *(const short8*)&w1p0[off];
        short8 a1 = *(const short8*)&w1p1[off];
        acc1[ot] = __builtin_amdgcn_mfma_f32_16x16x32_bf16(a0, xb0, acc1[ot], 0, 0, 0);
        acc1[ot] = __builtin_amdgcn_mfma_f32_16x16x32_bf16(a1, xb1, acc1[ot], 0, 0, 0);
      }
      union { unsigned u[4]; short8 s; } hb0, hb1;
      hb0.u[0] = pkt(gelu_f(acc1[0][0]), gelu_f(acc1[0][1]));
      hb0.u[1] = pkt(gelu_f(acc1[0][2]), gelu_f(acc1[0][3]));
      hb0.u[2] = pkt(gelu_f(acc1[1][0]), gelu_f(acc1[1][1]));
      hb0.u[3] = pkt(gelu_f(acc1[1][2]), gelu_f(acc1[1][3]));
      hb1.u[0] = pkt(gelu_f(acc1[2][0]), gelu_f(acc1[2][1]));
      hb1.u[1] = pkt(gelu_f(acc1[2][2]), gelu_f(acc1[2][3]));
      hb1.u[2] = pkt(gelu_f(acc1[3][0]), gelu_f(acc1[3][1]));
      hb1.u[3] = pkt(gelu_f(acc1[3][2]), gelu_f(acc1[3][3]));
#pragma unroll
      for (int ot = 0; ot < 4; ++ot) {
        const int off = ot * 16 * 128 + hf * 64;
        short8 w0 = *(const short8*)&w2p0[off];
        short8 w1 = *(const short8*)&w2p1[off];
        acc2[ot] = __builtin_amdgcn_mfma_f32_16x16x32_bf16(w0, hb0.s, acc2[ot], 0, 0, 0);
        acc2[ot] = __builtin_amdgcn_mfma_f32_16x16x32_bf16(w1, hb1.s, acc2[ot], 0, 0, 0);
      }
    }
    // store block-tile (RNE, final-quality rounding)
    unsigned short* yo = Yt1 + (size_t)np * TSZ
                       + (size_t)(chunk * 128 + wv * 32 + i * 16 + lr) * 64;
#pragma unroll
    for (int ot = 0; ot < 4; ++ot) {
      ushort4 ov;
      ov.x = f2bf(acc2[ot][0]);
      ov.y = f2bf(acc2[ot][1]);
      ov.z = f2bf(acc2[ot][2]);
      ov.w = f2bf(acc2[ot][3]);
      *(ushort4*)&yo[ot * 16 + q * 4] = ov;
    }
  }
}

// ---------------------------------------------------------------------------
// unpermute_k (unchanged from r12): Yt1 block-tile -> f32 row-major out,
// 1KB-contiguous writes per wave instruction.
// ---------------------------------------------------------------------------
__global__ __launch_bounds__(256) void unpermute_k(const unsigned short* __restrict__ Y,
                                                   float* __restrict__ out) {
  __shared__ unsigned short L[32 * 512];   // 32KB
  const int t = threadIdx.x, w = t >> 6, j = t & 63;
  const size_t r0 = (size_t)blockIdx.x * 8;
#pragma unroll
  for (int c = 0; c < 8; ++c) {
    const int n = w * 8 + c;
    short8 v = *(const short8*)(Y + (size_t)n * TSZ + r0 * 64 + j * 8);
    const int row = j >> 3;
    const int gp = (j & 7) ^ ((n + row) & 7);
    *(short8*)&L[n * 512 + row * 64 + gp * 8] = v;
  }
  __syncthreads();
#pragma unroll
  for (int p = 0; p < 2; ++p) {
    const int rloc = w * 2 + p;
    float* op = out + (r0 + rloc) * (size_t)D;
#pragma unroll
    for (int i = 0; i < 8; ++i) {
      const int cbase = i * 256 + j * 4;
      float4 f;
#pragma unroll
      for (int e = 0; e < 4; ++e) {
        const int cc   = cbase + e;
        const int npp  = cc >> 6, fp = cc & 63;
        const int n    = fp & 31;
        const int srow = (rloc & ~1) | (fp >> 5);
        const int scol = (rloc & 1) * 32 + npp;
        const int g    = ((scol >> 3) ^ ((n + srow) & 7));
        const float v  = bf2f(L[n * 512 + srow * 64 + g * 8 + (scol & 7)]);
        if      (e == 0) f.x = v;
        else if (e == 1) f.y = v;
        else if (e == 2) f.z = v;
        else             f.w = v;
      }
      *(float4*)&op[cbase] = f;
    }
  }
}

// W [n][R][C] f32 -> Wt [n][C][R] bf16, transposed + XOR-swizzled.
// W2 (odd segs) additionally k-slot-permuted (zero-DS H; validated r7-r12).
__global__ void prep_w_all(const float* __restrict__ W1_0, const float* __restrict__ W2_0,
                           const float* __restrict__ W1_1, const float* __restrict__ W2_1,
                           unsigned short* __restrict__ dst) {
  const int seg = blockIdx.x >> 10;
  const int id  = ((blockIdx.x & 1023) << 8) | threadIdx.x;
  const float* W; int R;
  if      (seg == 0) { W = W1_0; R = BD; }
  else if (seg == 1) { W = W2_0; R = HD; }
  else if (seg == 2) { W = W1_1; R = BD; }
  else               { W = W2_1; R = HD; }
  const int C   = (R == BD) ? HD : BD;
  const int n   = id >> 13;
  const int rem = id & 8191;
  const int c   = rem / R;
  const int r   = rem - c * R;
  const unsigned short val = f2bf(W[(n * R + r) * C + c]);
  if (seg & 1) {
    const int hf  = r >> 6, st = (r >> 5) & 1, blk = (r >> 4) & 1;
    const int qq  = (r & 15) >> 2, e = r & 3;
    const int slot = hf * 64 + st * 32 + qq * 8 + blk * 4 + e;
    dst[seg * WSZ + n * 8192 + c * HD + (slot ^ ((c & 7) << 3))] = val;
  } else {
    dst[seg * WSZ + n * 8192 + c * BD + (r ^ ((c & 7) << 3))] = val;
  }
}

extern "C" void kernel_launch(void* const* d_in, const int* in_sizes, int n_in,
                              void* d_out, int out_size, void* d_ws, size_t ws_size,
                              hipStream_t stream) {
  const float* x    = (const float*)d_in[0];
  const float* W1_0 = (const float*)d_in[1];
  const float* b1_0 = (const float*)d_in[2];
  const float* W2_0 = (const float*)d_in[3];
  const float* b2_0 = (const float*)d_in[4];
  const float* W1_1 = (const float*)d_in[5];
  const float* b1_1 = (const float*)d_in[6];
  const float* W2_1 = (const float*)d_in[7];
  const float* b2_1 = (const float*)d_in[8];
  float* out = (float*)d_out;

  // ws layout: [Wt 2MB][Yt0 64MB transposed][Yt1 64MB block-tile] = 130MB
  // (ws_size ~512MB per the harness's 524288KB poison fill)
  unsigned short* Wt  = (unsigned short*)d_ws;
  unsigned short* Yt0 = Wt + 4 * WSZ;
  unsigned short* Yt1 = Yt0 + (size_t)NB * TSZ;

  prep_w_all<<<4096, 256, 0, stream>>>(W1_0, W2_0, W1_1, W2_1, Wt);
  mlp0_k<<<4096, 256, 0, stream>>>(x, Yt0, Wt, Wt + WSZ, b1_0, b2_0);
  mlp1_k<<<4096, 256, 0, stream>>>(Yt0, Yt1, Wt + 2 * WSZ, Wt + 3 * WSZ, b1_1, b2_1);
  unpermute_k<<<2048, 256, 0, stream>>>(Yt1, out);
}